// Round 10
// baseline (5392.830 us; speedup 1.0000x reference)
//
#include <hip/hip_runtime.h>
#include <hip/hip_bf16.h>

// ---------------------------------------------------------------------------
// LSTM_66675072303478: 2-layer LSTM (B=512,S=128,E=7,H=1024) + FC(1024->672)
//
// v10: v9's fused single-flag round, split across TWO co-resident blocks/CU.
//  - 512 blocks (2/CU): L0-workers (K=1024 GEMM vs W0 + x-dot epilogue ->
//    h_a(r)) and L1-workers (K=2048 GEMM vs [Wi1|Wh1] + b1 epilogue ->
//    h_b(r-1)). Both wait cnt[mt] >= 64r, both increment -> still ONE sync
//    hop per round, but stalls of one block hide under the other's compute.
//  - Column-specialized XCDs (weights L2-resident), EA-point h stores,
//    plain cached h loads + 3-slot rotation + L1-only buffer_inv, LDS
//    double-buffered BK=64 K-loop with loads 2 iters ahead: all v8/v9-proven.
// ---------------------------------------------------------------------------

typedef __bf16 bf16x8 __attribute__((ext_vector_type(8)));
typedef float  f32x4  __attribute__((ext_vector_type(4)));

#define LDSTR 72            // LDS row stride in bf16 elems (64 data + 8 pad)
#define HSZ   (512 * 1024)  // one h buffer: 512 rows x 1024 cols (bf16)

__device__ __forceinline__ float sigm_f(float x) {
    x = fminf(30.f, fmaxf(-30.f, x));
    return 1.0f / (1.0f + __expf(-x));
}
__device__ __forceinline__ float tanh_f(float x) {
    x = fminf(30.f, fmaxf(-30.f, x));
    float e = __expf(-2.0f * x);
    return (1.0f - e) / (1.0f + e);
}

// n' = (j/16)*64 + g*16 + (j%16)  ->  original gate-major row g*1024 + j
__device__ __forceinline__ int perm_row(int np) {
    int g = (np >> 4) & 3;
    int j = ((np >> 6) << 4) | (np & 15);
    return g * 1024 + j;
}

// ---- relaxed-only flag ops (NO acquire/release -> no L2 inv/wb) ------------
__device__ __forceinline__ void spin_ge(const int* p, int target) {
    while (__hip_atomic_load(p, __ATOMIC_RELAXED, __HIP_MEMORY_SCOPE_AGENT) < target)
        __builtin_amdgcn_s_sleep(1);
}
__device__ __forceinline__ void signal_inc(int* p) {
    __hip_atomic_fetch_add(p, 1, __ATOMIC_RELAXED, __HIP_MEMORY_SCOPE_AGENT);
}
// L1-only invalidate (CU scope). Leaves L2/MALL intact; compiler fence.
__device__ __forceinline__ void inv_l1() {
    asm volatile("buffer_inv" ::: "memory");
}
// EA-point coherent dword store: bypasses L2s -> visible chip-wide.
__device__ __forceinline__ void store_ea(unsigned* p, unsigned v) {
    __hip_atomic_store(p, v, __ATOMIC_RELAXED, __HIP_MEMORY_SCOPE_AGENT);
}

// ---------------- weight prep kernels (run every call) ----------------------

__global__ void prep_w0(const float* __restrict__ Wh0, __bf16* __restrict__ W0p) {
    int idx = blockIdx.x * 256 + threadIdx.x;
    int np = idx >> 8, k4 = (idx & 255) << 2;
    int r = perm_row(np);
    float4 v = *(const float4*)(Wh0 + r * 1024 + k4);
    __bf16* o = W0p + np * 1024 + k4;
    o[0] = (__bf16)v.x; o[1] = (__bf16)v.y; o[2] = (__bf16)v.z; o[3] = (__bf16)v.w;
}

__global__ void prep_w1(const float* __restrict__ Wi1, const float* __restrict__ Wh1,
                        __bf16* __restrict__ W1p) {
    int idx = blockIdx.x * 256 + threadIdx.x;
    int np = idx >> 9, k4 = (idx & 511) << 2;
    int r = perm_row(np);
    const float* s = (k4 < 1024) ? (Wi1 + r * 1024 + k4) : (Wh1 + r * 1024 + (k4 - 1024));
    float4 v = *(const float4*)s;
    __bf16* o = W1p + np * 2048 + k4;
    o[0] = (__bf16)v.x; o[1] = (__bf16)v.y; o[2] = (__bf16)v.z; o[3] = (__bf16)v.w;
}

__global__ void prep_wfc(const float* __restrict__ Wfc, __bf16* __restrict__ Wfcp) {
    int idx = blockIdx.x * 256 + threadIdx.x;
    int n = idx >> 8, k4 = (idx & 255) << 2;
    __bf16* o = Wfcp + n * 1024 + k4;
    if (n < 672) {
        float4 v = *(const float4*)(Wfc + n * 1024 + k4);
        o[0] = (__bf16)v.x; o[1] = (__bf16)v.y; o[2] = (__bf16)v.z; o[3] = (__bf16)v.w;
    } else {
        o[0] = (__bf16)0.f; o[1] = (__bf16)0.f; o[2] = (__bf16)0.f; o[3] = (__bf16)0.f;
    }
}

__global__ void prep_small(const float* __restrict__ Wi0, const float* __restrict__ b0,
                           const float* __restrict__ b1,
                           float* __restrict__ Wi0p, float* __restrict__ b1p) {
    int np = blockIdx.x * 256 + threadIdx.x;
    int r = perm_row(np);
    float* o = Wi0p + np * 8;
    #pragma unroll
    for (int q = 0; q < 7; ++q) o[q] = Wi0[r * 7 + q];
    o[7] = b0[r];
    b1p[np] = b1[r];
}

// ---------------- single-B pipelined K=1024 sub-loop ------------------------
// Tile 64x128, 256 thr = 4 waves 2x2, BK=64, LDS double-buffer, 1 barrier/iter,
// global loads issued 2 iters ahead. Accumulates into acc (caller zeroes).

__device__ __forceinline__ void floopS(const __bf16* __restrict__ arow,
                                       const __bf16* __restrict__ wrow,
                                       int tid, __bf16* AldsB, __bf16* BldsB,
                                       f32x4 (&acc)[2][4]) {
    const int a_r = tid >> 2;
    const int a_c = (tid & 3) << 4;
    const int b_r = tid >> 1;
    const int b_c = (tid & 1) << 5;
    const int l  = tid & 63, w = tid >> 6;
    const int wm = w & 1,   wn = w >> 1;
    const int lj = l & 15,  lq = l >> 4;

    const __bf16* arw = arow + a_r * 1024 + a_c;

    uint4 ra0, ra1, rb0, rb1, rb2, rb3;
    auto ld = [&](int k0) {
        const __bf16* pa = arw + k0;
        ra0 = *(const uint4*)(pa);
        ra1 = *(const uint4*)(pa + 8);
        const __bf16* p = wrow + k0;
        rb0 = *(const uint4*)(p);      rb1 = *(const uint4*)(p + 8);
        rb2 = *(const uint4*)(p + 16); rb3 = *(const uint4*)(p + 24);
    };
    auto wr = [&](int buf) {
        __bf16* Al = AldsB + buf * (64 * LDSTR);
        *(uint4*)(Al + a_r * LDSTR + a_c)     = ra0;
        *(uint4*)(Al + a_r * LDSTR + a_c + 8) = ra1;
        __bf16* Bl = BldsB + buf * (128 * LDSTR);
        *(uint4*)(Bl + b_r * LDSTR + b_c)      = rb0;
        *(uint4*)(Bl + b_r * LDSTR + b_c + 8)  = rb1;
        *(uint4*)(Bl + b_r * LDSTR + b_c + 16) = rb2;
        *(uint4*)(Bl + b_r * LDSTR + b_c + 24) = rb3;
    };

    ld(0);
    wr(0);
    ld(64);
    __syncthreads();

    const __bf16* Ap = AldsB + (wm * 32 + lj) * LDSTR + lq * 8;
    const __bf16* Bp = BldsB + (wn * 64 + lj) * LDSTR + lq * 8;

    for (int it = 0; it < 16; ++it) {
        const int bo = it & 1;
        const __bf16* Ab = Ap + bo * (64 * LDSTR);
        const __bf16* Bb = Bp + bo * (128 * LDSTR);
        #pragma unroll
        for (int s = 0; s < 2; ++s) {
            bf16x8 af0 = *(const bf16x8*)(Ab + s * 32);
            bf16x8 af1 = *(const bf16x8*)(Ab + s * 32 + 16 * LDSTR);
            #pragma unroll
            for (int ni = 0; ni < 4; ++ni) {
                bf16x8 bfr = *(const bf16x8*)(Bb + s * 32 + ni * 16 * LDSTR);
                acc[0][ni] = __builtin_amdgcn_mfma_f32_16x16x32_bf16(af0, bfr, acc[0][ni], 0, 0, 0);
                acc[1][ni] = __builtin_amdgcn_mfma_f32_16x16x32_bf16(af1, bfr, acc[1][ni], 0, 0, 0);
            }
        }
        if (it + 1 < 16) wr((it + 1) & 1);       // data loaded 1 iter ago
        if (it + 2 < 16) ld((it + 2) * 64);      // 2-iter prefetch distance
        __syncthreads();
    }
}

// ---------------- persistent dual-worker LSTM kernel ------------------------
// 512 blocks, 2/CU. xcd owns gate-col slice [512x,512x+512) of both layers.
// Slot s in [0,64): isL1 = s>=32; mt = (s&31)>>2, nb = s&3.
// Round r (0..128): L0 workers compute L0(r) [r<128], L1 workers compute
// L1(r-1) [r>=1]; every worker incs cnt[mt] every round -> 64 incs/round.

__global__ __launch_bounds__(256, 2)
void lstm_persist(const float* __restrict__ x,
                  const __bf16* __restrict__ W0p, const __bf16* __restrict__ W1p,
                  const __bf16* __restrict__ Wfcp,
                  const float* __restrict__ Wi0p, const float* __restrict__ b1p,
                  const float* __restrict__ bfc,
                  __bf16* __restrict__ bufA, __bf16* __restrict__ bufB,
                  char* __restrict__ flagpage, float* __restrict__ out) {
    __shared__ __attribute__((aligned(16))) __bf16 Alds[2 * 64 * LDSTR];
    __shared__ __attribute__((aligned(16))) __bf16 Blds[2 * 128 * LDSTR];
    __shared__ float Aux1[128];
    __shared__ float Xlds[64 * 9];
    __shared__ float Wxlds[128 * 9];
    __shared__ int role[2];

    const int tid = threadIdx.x;

    // ---- claim XCD-local role ----
    if (tid == 0) {
        int xcd = __builtin_amdgcn_s_getreg(63508) & 7;   // HW_REG_XCC_ID
        int* xcnt = (int*)(flagpage + 1024) + xcd;
        int slot = __hip_atomic_fetch_add(xcnt, 1, __ATOMIC_RELAXED,
                                          __HIP_MEMORY_SCOPE_AGENT);
        role[0] = xcd; role[1] = slot;
    }
    __syncthreads();
    const int xcd = role[0];
    const int s   = role[1];          // 0..63
    const bool isL1 = (s >= 32);
    const int sl = s & 31;
    const int mt = sl >> 2, nb = sl & 3;
    const int m0 = mt * 64;
    const int n0 = xcd * 512 + nb * 128;
    int* cnt = (int*)(flagpage + (size_t)mt * 64);

    // one-time epilogue constants
    if (isL1) {
        if (tid < 128) Aux1[tid] = b1p[n0 + tid];
    } else {
        if (tid >= 128) {
            int nl = tid - 128;
            const float* sp = Wi0p + (n0 + nl) * 8;
            float* d = Wxlds + nl * 9;
            #pragma unroll
            for (int q = 0; q < 8; ++q) d[q] = sp[q];
        }
    }

    const int a_r = tid >> 2;
    const int a_c = (tid & 3) << 4;
    const int b_r = tid >> 1;
    const int b_c = (tid & 1) << 5;
    const int l  = tid & 63, w = tid >> 6;
    const int wm = w & 1,   wn = w >> 1;
    const int lj = l & 15,  lq = l >> 4;
    const int jc = (n0 >> 2) + wn * 16 + lj;   // h column in [0,1024)

    float cst[2][4];
    #pragma unroll
    for (int i = 0; i < 2; ++i)
        #pragma unroll
        for (int r = 0; r < 4; ++r) cst[i][r] = 0.f;

    f32x4 acc[2][4];

    if (!isL1) {
        // =============== L0 worker: h_a(r) = cell(h_a(r-1)@W0 + x.Wi0) ======
        const __bf16* w0row = W0p + (size_t)(n0 + b_r) * 1024 + b_c;
        for (int r = 0; r <= 128; ++r) {
            if (tid == 0) spin_ge(cnt, 64 * r);
            __syncthreads();
            inv_l1();
            if (r < 128) {
                const __bf16* haPrev = bufA + (size_t)(r % 3) * HSZ;
                __bf16*       haOut  = bufA + (size_t)((r + 1) % 3) * HSZ;

                if (tid < 64) {
                    const float* xr = x + (m0 + tid) * 896 + r * 7;
                    float* d = Xlds + tid * 9;
                    #pragma unroll
                    for (int q = 0; q < 7; ++q) d[q] = xr[q];
                    d[7] = 1.0f;
                }
                #pragma unroll
                for (int i = 0; i < 2; ++i)
                    #pragma unroll
                    for (int j = 0; j < 4; ++j)
                        acc[i][j] = (f32x4){0.f, 0.f, 0.f, 0.f};

                floopS(haPrev + m0 * 1024, w0row, tid, Alds, Blds, acc);

                #pragma unroll
                for (int mi = 0; mi < 2; ++mi) {
                    #pragma unroll
                    for (int rr = 0; rr < 4; ++rr) {
                        int ml = wm * 32 + mi * 16 + lq * 4 + rr;
                        int m  = m0 + ml;
                        float pre[4];
                        #pragma unroll
                        for (int g = 0; g < 4; ++g) pre[g] = acc[mi][g][rr];
                        const float* xr = Xlds + ml * 9;
                        #pragma unroll
                        for (int g = 0; g < 4; ++g) {
                            const float* wx = Wxlds + (wn * 64 + g * 16 + lj) * 9;
                            float sv = 0.f;
                            #pragma unroll
                            for (int q = 0; q < 8; ++q) sv += xr[q] * wx[q];
                            pre[g] += sv;
                        }
                        float ig = sigm_f(pre[0]);
                        float fg = sigm_f(pre[1]);
                        float gv = tanh_f(pre[2]);
                        float og = sigm_f(pre[3]);
                        float cn = fg * cst[mi][rr] + ig * gv;
                        cst[mi][rr] = cn;
                        float hv = og * tanh_f(cn);
                        unsigned u32 = __builtin_bit_cast(unsigned, hv);
                        unsigned hu = (u32 + 0x7fffu + ((u32 >> 16) & 1u)) >> 16;
                        int pv = __shfl_xor((int)hu, 1, 64);
                        if ((lj & 1) == 0)
                            store_ea((unsigned*)(haOut + (size_t)m * 1024 + jc),
                                     hu | ((unsigned)pv << 16));
                    }
                }
            }
            __syncthreads();             // vmcnt(0): EA stores performed
            if (tid == 0) signal_inc(cnt);
        }

        // ---- final FC (L0 workers nb==0, xcd<6): out = h_b(127)@Wfc^T ------
        if (nb == 0 && xcd < 6) {
            const int n0fc = xcd * 128;
            if (tid == 0) spin_ge(cnt, 64 * 129);
            __syncthreads();
            inv_l1();
            if (tid < 128) {
                int n = n0fc + tid;
                Aux1[tid] = (n < 672) ? bfc[n] : 0.f;
            }
            #pragma unroll
            for (int i = 0; i < 2; ++i)
                #pragma unroll
                for (int j = 0; j < 4; ++j)
                    acc[i][j] = (f32x4){0.f, 0.f, 0.f, 0.f};
            // h_b(127) written in round 128 into bufB slot 128%3 = 2
            floopS(bufB + (size_t)2 * HSZ + m0 * 1024,
                   Wfcp + (size_t)(n0fc + b_r) * 1024 + b_c,
                   tid, Alds, Blds, acc);
            #pragma unroll
            for (int mi = 0; mi < 2; ++mi) {
                #pragma unroll
                for (int rr = 0; rr < 4; ++rr) {
                    int m = m0 + wm * 32 + mi * 16 + lq * 4 + rr;
                    #pragma unroll
                    for (int ni = 0; ni < 4; ++ni) {
                        int n = n0fc + wn * 64 + ni * 16 + lj;
                        if (n < 672)
                            out[m * 672 + n] = acc[mi][ni][rr] + Aux1[wn * 64 + ni * 16 + lj];
                    }
                }
            }
        }
    } else {
        // ====== L1 worker: h_b(r-1) = cell([h_a(r-1)|h_b(r-2)]@W1 + b1) =====
        const __bf16* w1row = W1p + (size_t)(n0 + b_r) * 2048 + b_c;
        for (int r = 0; r <= 128; ++r) {
            if (tid == 0) spin_ge(cnt, 64 * r);
            __syncthreads();
            inv_l1();
            if (r >= 1) {
                const __bf16* haPrev = bufA + (size_t)(r % 3) * HSZ;        // h_a(r-1)
                const __bf16* hbPrev = bufB + (size_t)((r + 2) % 3) * HSZ;  // h_b(r-2)
                __bf16*       hbOut  = bufB + (size_t)(r % 3) * HSZ;        // h_b(r-1)

                #pragma unroll
                for (int i = 0; i < 2; ++i)
                    #pragma unroll
                    for (int j = 0; j < 4; ++j)
                        acc[i][j] = (f32x4){0.f, 0.f, 0.f, 0.f};

                floopS(haPrev + m0 * 1024, w1row,        tid, Alds, Blds, acc);
                floopS(hbPrev + m0 * 1024, w1row + 1024, tid, Alds, Blds, acc);

                #pragma unroll
                for (int mi = 0; mi < 2; ++mi) {
                    #pragma unroll
                    for (int rr = 0; rr < 4; ++rr) {
                        int m = m0 + wm * 32 + mi * 16 + lq * 4 + rr;
                        float pre[4];
                        #pragma unroll
                        for (int g = 0; g < 4; ++g)
                            pre[g] = acc[mi][g][rr] + Aux1[wn * 64 + g * 16 + lj];
                        float ig = sigm_f(pre[0]);
                        float fg = sigm_f(pre[1]);
                        float gv = tanh_f(pre[2]);
                        float og = sigm_f(pre[3]);
                        float cn = fg * cst[mi][rr] + ig * gv;
                        cst[mi][rr] = cn;
                        float hv = og * tanh_f(cn);
                        unsigned u32 = __builtin_bit_cast(unsigned, hv);
                        unsigned hu = (u32 + 0x7fffu + ((u32 >> 16) & 1u)) >> 16;
                        int pv = __shfl_xor((int)hu, 1, 64);
                        if ((lj & 1) == 0)
                            store_ea((unsigned*)(hbOut + (size_t)m * 1024 + jc),
                                     hu | ((unsigned)pv << 16));
                    }
                }
            }
            __syncthreads();             // vmcnt(0): EA stores performed
            if (tid == 0) signal_inc(cnt);
        }
    }
}

// ---------------- workspace layout (bytes) ----------------------------------
#define O_W0P   0u            // 4096*1024*2  = 8388608
#define O_W1P   8388608u      // 4096*2048*2  = 16777216
#define O_WFCP  25165824u     // 768*1024*2   = 1572864
#define O_WI0P  26738688u     // 4096*8*4     = 131072
#define O_B1P   26869760u     // 4096*4       = 16384
#define O_FLG   26886144u     // 2048: cnt[8]@mt*64, xcnt@1024
#define O_BA    26888192u     // bufA[3] = 3*1048576  (slot0 zeroed = h_a(-1))
#define O_BB    30033920u     // bufB[3] = 3*1048576  (slot0 zeroed = h_b(-1))
#define WS_NEED 33179648u

extern "C" void kernel_launch(void* const* d_in, const int* in_sizes, int n_in,
                              void* d_out, int out_size, void* d_ws, size_t ws_size,
                              hipStream_t stream) {
    const float* x   = (const float*)d_in[0];
    const float* Wi0 = (const float*)d_in[1];
    const float* Wh0 = (const float*)d_in[2];
    const float* b0  = (const float*)d_in[3];
    const float* Wi1 = (const float*)d_in[4];
    const float* Wh1 = (const float*)d_in[5];
    const float* b1  = (const float*)d_in[6];
    const float* Wfc = (const float*)d_in[7];
    const float* bfc = (const float*)d_in[8];
    float* out = (float*)d_out;
    char*  ws  = (char*)d_ws;
    if (ws_size < WS_NEED) return;

    __bf16* W0p  = (__bf16*)(ws + O_W0P);
    __bf16* W1p  = (__bf16*)(ws + O_W1P);
    __bf16* Wfcp = (__bf16*)(ws + O_WFCP);
    float*  Wi0p = (float*)(ws + O_WI0P);
    float*  b1p  = (float*)(ws + O_B1P);
    char*   flg  = (char*)(ws + O_FLG);
    __bf16* bufA = (__bf16*)(ws + O_BA);
    __bf16* bufB = (__bf16*)(ws + O_BB);

    // zero flags + bufA slot0 (contiguous), and bufB slot0
    hipMemsetAsync(ws + O_FLG, 0, 2048u + 1048576u, stream);
    hipMemsetAsync(ws + O_BB, 0, 1048576u, stream);

    prep_w0   <<<4096, 256, 0, stream>>>(Wh0, W0p);
    prep_w1   <<<8192, 256, 0, stream>>>(Wi1, Wh1, W1p);
    prep_wfc  <<<768,  256, 0, stream>>>(Wfc, Wfcp);
    prep_small<<<16,   256, 0, stream>>>(Wi0, b0, b1, Wi0p, b1p);

    lstm_persist<<<512, 256, 0, stream>>>(x, W0p, W1p, Wfcp, Wi0p, b1p, bfc,
                                          bufA, bufB, flg, out);
}

// Round 11
// 3391.191 us; speedup vs baseline: 1.5902x; 1.5902x over previous
//
#include <hip/hip_runtime.h>
#include <hip/hip_bf16.h>

// ---------------------------------------------------------------------------
// LSTM_66675072303478: 2-layer LSTM (B=512,S=128,E=7,H=1024) + FC(1024->672)
//
// v11 = v9 (fused single-flag round, column-specialized XCDs) with 512-thread
// blocks: 8 waves in a 4(m)x2(n) grid over the same 64x128 tile -> 2 waves
// per SIMD hide ds_read->MFMA and global-load latency (v9 ran 1 wave/SIMD:
// MfmaUtil 17%, 58% idle). All blocks remain IDENTICAL (v10's heterogeneous
// workers regressed: random same-type pairing on a CU serialized rounds).
//  - Wave tile 16x64: n-width 64 keeps all 4 gates of a hidden column in one
//    wave (gate-interleaved epilogue unchanged).
//  - Everything else proven: weights L2-resident per XCD, EA-point h stores,
//    cached h loads + 3-slot rotation + L1-only buffer_inv, one flag/round.
// ---------------------------------------------------------------------------

typedef __bf16 bf16x8 __attribute__((ext_vector_type(8)));
typedef float  f32x4  __attribute__((ext_vector_type(4)));

#define LDSTR 72            // LDS row stride in bf16 elems (64 data + 8 pad)
#define HSZ   (512 * 1024)  // one h buffer: 512 rows x 1024 cols (bf16)

__device__ __forceinline__ float sigm_f(float x) {
    x = fminf(30.f, fmaxf(-30.f, x));
    return 1.0f / (1.0f + __expf(-x));
}
__device__ __forceinline__ float tanh_f(float x) {
    x = fminf(30.f, fmaxf(-30.f, x));
    float e = __expf(-2.0f * x);
    return (1.0f - e) / (1.0f + e);
}

// n' = (j/16)*64 + g*16 + (j%16)  ->  original gate-major row g*1024 + j
__device__ __forceinline__ int perm_row(int np) {
    int g = (np >> 4) & 3;
    int j = ((np >> 6) << 4) | (np & 15);
    return g * 1024 + j;
}

// ---- relaxed-only flag ops (NO acquire/release -> no L2 inv/wb) ------------
__device__ __forceinline__ void spin_ge(const int* p, int target) {
    while (__hip_atomic_load(p, __ATOMIC_RELAXED, __HIP_MEMORY_SCOPE_AGENT) < target)
        __builtin_amdgcn_s_sleep(1);
}
__device__ __forceinline__ void signal_inc(int* p) {
    __hip_atomic_fetch_add(p, 1, __ATOMIC_RELAXED, __HIP_MEMORY_SCOPE_AGENT);
}
// L1-only invalidate (CU scope). Leaves L2/MALL intact; compiler fence.
__device__ __forceinline__ void inv_l1() {
    asm volatile("buffer_inv" ::: "memory");
}
// EA-point coherent dword store: bypasses L2s -> visible chip-wide.
__device__ __forceinline__ void store_ea(unsigned* p, unsigned v) {
    __hip_atomic_store(p, v, __ATOMIC_RELAXED, __HIP_MEMORY_SCOPE_AGENT);
}

// ---------------- weight prep kernels (run every call) ----------------------

__global__ void prep_w0(const float* __restrict__ Wh0, __bf16* __restrict__ W0p) {
    int idx = blockIdx.x * 256 + threadIdx.x;
    int np = idx >> 8, k4 = (idx & 255) << 2;
    int r = perm_row(np);
    float4 v = *(const float4*)(Wh0 + r * 1024 + k4);
    __bf16* o = W0p + np * 1024 + k4;
    o[0] = (__bf16)v.x; o[1] = (__bf16)v.y; o[2] = (__bf16)v.z; o[3] = (__bf16)v.w;
}

__global__ void prep_w1(const float* __restrict__ Wi1, const float* __restrict__ Wh1,
                        __bf16* __restrict__ W1p) {
    int idx = blockIdx.x * 256 + threadIdx.x;
    int np = idx >> 9, k4 = (idx & 511) << 2;
    int r = perm_row(np);
    const float* s = (k4 < 1024) ? (Wi1 + r * 1024 + k4) : (Wh1 + r * 1024 + (k4 - 1024));
    float4 v = *(const float4*)s;
    __bf16* o = W1p + np * 2048 + k4;
    o[0] = (__bf16)v.x; o[1] = (__bf16)v.y; o[2] = (__bf16)v.z; o[3] = (__bf16)v.w;
}

__global__ void prep_wfc(const float* __restrict__ Wfc, __bf16* __restrict__ Wfcp) {
    int idx = blockIdx.x * 256 + threadIdx.x;
    int n = idx >> 8, k4 = (idx & 255) << 2;
    __bf16* o = Wfcp + n * 1024 + k4;
    if (n < 672) {
        float4 v = *(const float4*)(Wfc + n * 1024 + k4);
        o[0] = (__bf16)v.x; o[1] = (__bf16)v.y; o[2] = (__bf16)v.z; o[3] = (__bf16)v.w;
    } else {
        o[0] = (__bf16)0.f; o[1] = (__bf16)0.f; o[2] = (__bf16)0.f; o[3] = (__bf16)0.f;
    }
}

__global__ void prep_small(const float* __restrict__ Wi0, const float* __restrict__ b0,
                           const float* __restrict__ b1,
                           float* __restrict__ Wi0p, float* __restrict__ b1p) {
    int np = blockIdx.x * 256 + threadIdx.x;
    int r = perm_row(np);
    float* o = Wi0p + np * 8;
    #pragma unroll
    for (int q = 0; q < 7; ++q) o[q] = Wi0[r * 7 + q];
    o[7] = b0[r];
    b1p[np] = b1[r];
}

// ---------------- fused pipelined K=1024 sub-loop (512 threads) -------------
// Tile 64x128, 8 waves in 4(m)x2(n), wave tile 16x64, BK=64, LDS dbuf,
// 1 barrier/iter, global loads 2 iters ahead. D0 -> acc0 (W0), D1 -> acc1.

template <bool D0, bool D1>
__device__ __forceinline__ void floop(const __bf16* __restrict__ abase,
                                      const __bf16* __restrict__ w0row,
                                      const __bf16* __restrict__ w1row,
                                      int tid,
                                      __bf16* AldsB, __bf16* B0ldsB, __bf16* B1ldsB,
                                      f32x4 (&acc0)[4], f32x4 (&acc1)[4]) {
    const int a_r = tid >> 3;             // 0..63
    const int a_c = (tid & 7) << 3;       // 0..56 step 8 (16 B)
    const int b_r = tid >> 2;             // 0..127
    const int b_c = (tid & 3) << 4;       // 0,16,32,48 (2 x 16 B each)
    const int l  = tid & 63, w = tid >> 6;
    const int wm = w & 3,   wn = w >> 2;
    const int lj = l & 15,  lq = l >> 4;

    const __bf16* arw = abase + a_r * 1024 + a_c;

    uint4 ra, rb00, rb01, rb10, rb11;
    auto ld = [&](int k0) {
        ra = *(const uint4*)(arw + k0);
        if (D0) {
            const __bf16* p = w0row + k0;
            rb00 = *(const uint4*)(p);
            rb01 = *(const uint4*)(p + 8);
        }
        if (D1) {
            const __bf16* p = w1row + k0;
            rb10 = *(const uint4*)(p);
            rb11 = *(const uint4*)(p + 8);
        }
    };
    auto wr = [&](int buf) {
        *(uint4*)(AldsB + buf * (64 * LDSTR) + a_r * LDSTR + a_c) = ra;
        if (D0) {
            __bf16* Bl = B0ldsB + buf * (128 * LDSTR) + b_r * LDSTR + b_c;
            *(uint4*)(Bl)     = rb00;
            *(uint4*)(Bl + 8) = rb01;
        }
        if (D1) {
            __bf16* Bl = B1ldsB + buf * (128 * LDSTR) + b_r * LDSTR + b_c;
            *(uint4*)(Bl)     = rb10;
            *(uint4*)(Bl + 8) = rb11;
        }
    };

    ld(0);
    wr(0);
    ld(64);
    __syncthreads();

    const __bf16* Ap  = AldsB  + (wm * 16 + lj) * LDSTR + lq * 8;
    const __bf16* B0p = B0ldsB + (wn * 64 + lj) * LDSTR + lq * 8;
    const __bf16* B1p = B1ldsB + (wn * 64 + lj) * LDSTR + lq * 8;

    for (int it = 0; it < 16; ++it) {
        const int bo = it & 1;
        const __bf16* Ab  = Ap  + bo * (64 * LDSTR);
        const __bf16* B0b = B0p + bo * (128 * LDSTR);
        const __bf16* B1b = B1p + bo * (128 * LDSTR);
        #pragma unroll
        for (int s = 0; s < 2; ++s) {
            bf16x8 af = *(const bf16x8*)(Ab + s * 32);
            #pragma unroll
            for (int ni = 0; ni < 4; ++ni) {
                if (D0) {
                    bf16x8 b0 = *(const bf16x8*)(B0b + s * 32 + ni * 16 * LDSTR);
                    acc0[ni] = __builtin_amdgcn_mfma_f32_16x16x32_bf16(af, b0, acc0[ni], 0, 0, 0);
                }
                if (D1) {
                    bf16x8 b1 = *(const bf16x8*)(B1b + s * 32 + ni * 16 * LDSTR);
                    acc1[ni] = __builtin_amdgcn_mfma_f32_16x16x32_bf16(af, b1, acc1[ni], 0, 0, 0);
                }
            }
        }
        if (it + 1 < 16) wr((it + 1) & 1);       // data loaded 1 iter ago
        if (it + 2 < 16) ld((it + 2) * 64);      // 2-iter prefetch distance
        __syncthreads();
    }
}

// ---------------- persistent fused LSTM kernel ------------------------------
// 256 blocks, 1/CU, 512 threads. xcd owns gate-col slice [512x,512x+512);
// slot -> mt (0..7) x nb (0..3). Round r: L0(r) [r<128] + L1(r-1) [r>0];
// one flag inc per round; cnt[mt] target 32*r.

__global__ __launch_bounds__(512)
void lstm_persist(const float* __restrict__ x,
                  const __bf16* __restrict__ W0p, const __bf16* __restrict__ W1p,
                  const __bf16* __restrict__ Wfcp,
                  const float* __restrict__ Wi0p, const float* __restrict__ b1p,
                  const float* __restrict__ bfc,
                  __bf16* __restrict__ bufA, __bf16* __restrict__ bufB,
                  char* __restrict__ flagpage, float* __restrict__ out) {
    __shared__ __attribute__((aligned(16))) __bf16 Alds[2 * 64 * LDSTR];
    __shared__ __attribute__((aligned(16))) __bf16 B0lds[2 * 128 * LDSTR];
    __shared__ __attribute__((aligned(16))) __bf16 B1lds[2 * 128 * LDSTR];
    __shared__ float Aux1[128];
    __shared__ float Xlds[64 * 9];
    __shared__ float Wxlds[128 * 9];
    __shared__ int role[2];

    const int tid = threadIdx.x;

    // ---- claim XCD-local role ----
    if (tid == 0) {
        int xcd = __builtin_amdgcn_s_getreg(63508) & 7;   // HW_REG_XCC_ID
        int* xcnt = (int*)(flagpage + 1024) + xcd;
        int slot = __hip_atomic_fetch_add(xcnt, 1, __ATOMIC_RELAXED,
                                          __HIP_MEMORY_SCOPE_AGENT);
        role[0] = xcd; role[1] = slot;
    }
    __syncthreads();
    const int xcd = role[0];
    const int sl  = role[1];          // 0..31
    const int mt = sl >> 2, nb = sl & 3;
    const int m0 = mt * 64;
    const int n0 = xcd * 512 + nb * 128;
    int* cnt = (int*)(flagpage + (size_t)mt * 64);

    // one-time epilogue constants
    if (tid < 128) {
        Aux1[tid] = b1p[n0 + tid];
    } else if (tid < 256) {
        int nl = tid - 128;
        const float* sp = Wi0p + (n0 + nl) * 8;
        float* d = Wxlds + nl * 9;
        #pragma unroll
        for (int q = 0; q < 8; ++q) d[q] = sp[q];
    }

    const int b_r = tid >> 2;
    const int b_c = (tid & 3) << 4;
    const int l  = tid & 63, w = tid >> 6;
    const int wm = w & 3,   wn = w >> 2;
    const int lj = l & 15,  lq = l >> 4;
    const int jc = (n0 >> 2) + wn * 16 + lj;   // h column in [0,1024)

    const __bf16* w0row = W0p + (size_t)(n0 + b_r) * 1024 + b_c;
    const __bf16* w1row = W1p + (size_t)(n0 + b_r) * 2048 + b_c;

    float c0[4], c1[4];
    #pragma unroll
    for (int r = 0; r < 4; ++r) { c0[r] = 0.f; c1[r] = 0.f; }

    f32x4 acc0[4], acc1[4];

    for (int r = 0; r <= 128; ++r) {
        const bool do0 = (r < 128), do1 = (r > 0);
        const __bf16* haPrev = bufA + (size_t)(r % 3) * HSZ;        // h_a(r-1)
        __bf16*       haOut  = bufA + (size_t)((r + 1) % 3) * HSZ;  // h_a(r)
        const __bf16* hbPrev = bufB + (size_t)((r + 2) % 3) * HSZ;  // h_b(r-2)
        __bf16*       hbOut  = bufB + (size_t)(r % 3) * HSZ;        // h_b(r-1)

        if (tid == 0) spin_ge(cnt, 32 * r);
        __syncthreads();
        inv_l1();

        // stage x_r (read-only input)
        if (do0 && tid < 64) {
            const float* xr = x + (m0 + tid) * 896 + r * 7;
            float* d = Xlds + tid * 9;
            #pragma unroll
            for (int q = 0; q < 7; ++q) d[q] = xr[q];
            d[7] = 1.0f;
        }

        #pragma unroll
        for (int j = 0; j < 4; ++j) {
            acc0[j] = (f32x4){0.f, 0.f, 0.f, 0.f};
            acc1[j] = (f32x4){0.f, 0.f, 0.f, 0.f};
        }

        const __bf16* abase = haPrev + m0 * 1024;
        if (do0 && do1)
            floop<true, true >(abase, w0row, w1row, tid, Alds, B0lds, B1lds, acc0, acc1);
        else if (do0)
            floop<true, false>(abase, w0row, w1row, tid, Alds, B0lds, B1lds, acc0, acc1);
        else
            floop<false, true>(abase, w0row, w1row, tid, Alds, B0lds, B1lds, acc0, acc1);

        if (do1) {   // h_b(r-2) half of layer-1 GEMM (k in [1024,2048))
            floop<false, true>(hbPrev + m0 * 1024, w0row, w1row + 1024,
                               tid, Alds, B0lds, B1lds, acc0, acc1);
        }

        if (do0) {   // L0 epilogue: cell update + EA store h_a(r)
            #pragma unroll
            for (int rr = 0; rr < 4; ++rr) {
                int ml = wm * 16 + lq * 4 + rr;
                int m  = m0 + ml;
                float pre[4];
                #pragma unroll
                for (int g = 0; g < 4; ++g) pre[g] = acc0[g][rr];
                const float* xr = Xlds + ml * 9;
                #pragma unroll
                for (int g = 0; g < 4; ++g) {
                    const float* wx = Wxlds + (wn * 64 + g * 16 + lj) * 9;
                    float sv = 0.f;
                    #pragma unroll
                    for (int q = 0; q < 8; ++q) sv += xr[q] * wx[q];
                    pre[g] += sv;
                }
                float ig = sigm_f(pre[0]);
                float fg = sigm_f(pre[1]);
                float gv = tanh_f(pre[2]);
                float og = sigm_f(pre[3]);
                float cn = fg * c0[rr] + ig * gv;
                c0[rr] = cn;
                float hv = og * tanh_f(cn);
                unsigned u32 = __builtin_bit_cast(unsigned, hv);
                unsigned hu = (u32 + 0x7fffu + ((u32 >> 16) & 1u)) >> 16;
                int pv = __shfl_xor((int)hu, 1, 64);
                if ((lj & 1) == 0)
                    store_ea((unsigned*)(haOut + (size_t)m * 1024 + jc),
                             hu | ((unsigned)pv << 16));
            }
        }
        if (do1) {   // L1 epilogue: cell update + EA store h_b(r-1)
            #pragma unroll
            for (int rr = 0; rr < 4; ++rr) {
                int m = m0 + wm * 16 + lq * 4 + rr;
                float pre[4];
                #pragma unroll
                for (int g = 0; g < 4; ++g)
                    pre[g] = acc1[g][rr] + Aux1[wn * 64 + g * 16 + lj];
                float ig = sigm_f(pre[0]);
                float fg = sigm_f(pre[1]);
                float gv = tanh_f(pre[2]);
                float og = sigm_f(pre[3]);
                float cn = fg * c1[rr] + ig * gv;
                c1[rr] = cn;
                float hv = og * tanh_f(cn);
                unsigned u32 = __builtin_bit_cast(unsigned, hv);
                unsigned hu = (u32 + 0x7fffu + ((u32 >> 16) & 1u)) >> 16;
                int pv = __shfl_xor((int)hu, 1, 64);
                if ((lj & 1) == 0)
                    store_ea((unsigned*)(hbOut + (size_t)m * 1024 + jc),
                             hu | ((unsigned)pv << 16));
            }
        }
        __syncthreads();                 // vmcnt(0): EA stores performed
        if (tid == 0) signal_inc(cnt);
    }

    // ---- final FC: pred = h_b(127) @ Wfc^T + bfc  (nb==0, xcd<6) -----------
    if (nb == 0 && xcd < 6) {
        const int n0fc = xcd * 128;
        if (tid == 0) spin_ge(cnt, 32 * 129);
        __syncthreads();
        inv_l1();
        if (tid < 128) {
            int n = n0fc + tid;
            Aux1[tid] = (n < 672) ? bfc[n] : 0.f;
        }
        #pragma unroll
        for (int j = 0; j < 4; ++j)
            acc0[j] = (f32x4){0.f, 0.f, 0.f, 0.f};
        // h_b(127) written in round 128 into bufB slot 128%3 = 2
        floop<true, false>(bufB + (size_t)2 * HSZ + m0 * 1024,
                           Wfcp + (size_t)(n0fc + b_r) * 1024 + b_c, nullptr,
                           tid, Alds, B0lds, B1lds, acc0, acc1);
        #pragma unroll
        for (int rr = 0; rr < 4; ++rr) {
            int m = m0 + wm * 16 + lq * 4 + rr;
            #pragma unroll
            for (int ni = 0; ni < 4; ++ni) {
                int n = n0fc + wn * 64 + ni * 16 + lj;
                if (n < 672)
                    out[m * 672 + n] = acc0[ni][rr] + Aux1[wn * 64 + ni * 16 + lj];
            }
        }
    }
}

// ---------------- workspace layout (bytes) ----------------------------------
#define O_W0P   0u            // 4096*1024*2  = 8388608
#define O_W1P   8388608u      // 4096*2048*2  = 16777216
#define O_WFCP  25165824u     // 768*1024*2   = 1572864
#define O_WI0P  26738688u     // 4096*8*4     = 131072
#define O_B1P   26869760u     // 4096*4       = 16384
#define O_FLG   26886144u     // 2048: cnt[8]@mt*64, xcnt@1024
#define O_BA    26888192u     // bufA[3] = 3*1048576  (slot0 zeroed = h_a(-1))
#define O_BB    30033920u     // bufB[3] = 3*1048576  (slot0 zeroed = h_b(-1))
#define WS_NEED 33179648u

extern "C" void kernel_launch(void* const* d_in, const int* in_sizes, int n_in,
                              void* d_out, int out_size, void* d_ws, size_t ws_size,
                              hipStream_t stream) {
    const float* x   = (const float*)d_in[0];
    const float* Wi0 = (const float*)d_in[1];
    const float* Wh0 = (const float*)d_in[2];
    const float* b0  = (const float*)d_in[3];
    const float* Wi1 = (const float*)d_in[4];
    const float* Wh1 = (const float*)d_in[5];
    const float* b1  = (const float*)d_in[6];
    const float* Wfc = (const float*)d_in[7];
    const float* bfc = (const float*)d_in[8];
    float* out = (float*)d_out;
    char*  ws  = (char*)d_ws;
    if (ws_size < WS_NEED) return;

    __bf16* W0p  = (__bf16*)(ws + O_W0P);
    __bf16* W1p  = (__bf16*)(ws + O_W1P);
    __bf16* Wfcp = (__bf16*)(ws + O_WFCP);
    float*  Wi0p = (float*)(ws + O_WI0P);
    float*  b1p  = (float*)(ws + O_B1P);
    char*   flg  = (char*)(ws + O_FLG);
    __bf16* bufA = (__bf16*)(ws + O_BA);
    __bf16* bufB = (__bf16*)(ws + O_BB);

    // zero flags + bufA slot0 (contiguous), and bufB slot0
    hipMemsetAsync(ws + O_FLG, 0, 2048u + 1048576u, stream);
    hipMemsetAsync(ws + O_BB, 0, 1048576u, stream);

    prep_w0   <<<4096, 256, 0, stream>>>(Wh0, W0p);
    prep_w1   <<<8192, 256, 0, stream>>>(Wi1, Wh1, W1p);
    prep_wfc  <<<768,  256, 0, stream>>>(Wfc, Wfcp);
    prep_small<<<16,   256, 0, stream>>>(Wi0, b0, b1, Wi0p, b1p);

    lstm_persist<<<256, 512, 0, stream>>>(x, W0p, W1p, Wfcp, Wi0p, b1p, bfc,
                                          bufA, bufB, flg, out);
}